// Round 2
// baseline (429.638 us; speedup 1.0000x reference)
//
#include <hip/hip_runtime.h>

#define NN 100000
#define NE 1600000
#define DF 128
#define NB 98   // (NN + 1023) / 1024, scan blocks

typedef short short8 __attribute__((ext_vector_type(8)));
typedef float floatx4 __attribute__((ext_vector_type(4)));
typedef float floatx2 __attribute__((ext_vector_type(2)));
typedef unsigned int uint;
typedef unsigned short ushort;

// float -> bf16 (RNE; inputs finite)
static __device__ __forceinline__ ushort f2bf(float f) {
    uint u = __builtin_bit_cast(uint, f);
    return (ushort)((u + 0x7fffu + ((u >> 16) & 1u)) >> 16);
}
static __device__ __forceinline__ float bf2f_lo(uint v) {
    return __builtin_bit_cast(float, v << 16);
}
static __device__ __forceinline__ float bf2f_hi(uint v) {
    return __builtin_bit_cast(float, v & 0xffff0000u);
}

// ---------------------------------------------------------------------------
// CSR build: degree count -> block scan -> scatter into sorted_src.
// ---------------------------------------------------------------------------
__global__ void count_deg(const int* __restrict__ dst, int* __restrict__ cnt) {
    int e = blockIdx.x * blockDim.x + threadIdx.x;
    if (e < NE) atomicAdd(&cnt[dst[e]], 1);
}

__global__ __launch_bounds__(1024) void k_bsum(const int* __restrict__ cnt,
                                               int* __restrict__ bsum) {
    __shared__ int s[1024];
    int tid = threadIdx.x;
    int i = blockIdx.x * 1024 + tid;
    s[tid] = (i < NN) ? cnt[i] : 0;
    __syncthreads();
    for (int st = 512; st > 0; st >>= 1) {
        if (tid < st) s[tid] += s[tid + st];
        __syncthreads();
    }
    if (tid == 0) bsum[blockIdx.x] = s[0];
}

__global__ void k_scan_sums(int* bsum) {  // exclusive scan of NB values, 1 block
    __shared__ int s[128];
    int tid = threadIdx.x;
    int v = (tid < NB) ? bsum[tid] : 0;
    s[tid] = v;
    __syncthreads();
    for (int st = 1; st < 128; st <<= 1) {
        int t = (tid >= st) ? s[tid - st] : 0;
        __syncthreads();
        s[tid] += t;
        __syncthreads();
    }
    if (tid < NB) bsum[tid] = s[tid] - v;  // exclusive
}

// exclusive scan within each 1024-block + block offset -> off[i]; cur[i]=off[i]
__global__ __launch_bounds__(1024) void k_scan_block(const int* cnt,
                                                     const int* __restrict__ bsum,
                                                     int* __restrict__ off, int* cur) {
    __shared__ int s[2][1024];
    int tid = threadIdx.x;
    int i = blockIdx.x * 1024 + tid;
    int v = (i < NN) ? cnt[i] : 0;
    int b = 0;
    s[0][tid] = v;
    __syncthreads();
    for (int st = 1; st < 1024; st <<= 1) {
        int t = s[b][tid] + ((tid >= st) ? s[b][tid - st] : 0);
        s[b ^ 1][tid] = t;
        __syncthreads();
        b ^= 1;
    }
    int exc = s[b][tid] - v + bsum[blockIdx.x];
    if (i < NN) { off[i] = exc; cur[i] = exc; }
}

// Scatter with NON-TEMPORAL stores: random 4B plain stores replicate dirty
// 64B lines in all 8 per-XCD L2s (R1: 105MB WRITE_SIZE for a 6.4MB array).
// nt stores bypass the XCD L2 dirty path and merge memory-side.
__global__ void k_scatter(const int* __restrict__ src, const int* __restrict__ dst,
                          int* __restrict__ cur, int* __restrict__ srt) {
    int e = blockIdx.x * blockDim.x + threadIdx.x;
    if (e < NE) {
        int s = src[e];
        int pos = atomicAdd(&cur[dst[e]], 1);
        __builtin_nontemporal_store(s, &srt[pos]);
    }
}

// ---------------------------------------------------------------------------
// x (fp32) -> xb (bf16 row-major) + xf8c (fp8 e4m3, CHUNK-MAJOR: 4 slabs of
// 32 fp8 columns; slab p is contiguous NN x 32B -> 3.2 MB, L2-resident)
// ---------------------------------------------------------------------------
__global__ void conv_x_kernel(const float* __restrict__ x, ushort* __restrict__ xb,
                              uint* __restrict__ xf8c) {
    int i = blockIdx.x * 256 + threadIdx.x;
    if (i < NN * DF / 4) {
        float4 v = ((const float4*)x)[i];
        uint lo = (uint)f2bf(v.x) | ((uint)f2bf(v.y) << 16);
        uint hi = (uint)f2bf(v.z) | ((uint)f2bf(v.w) << 16);
        ((uint2*)xb)[i] = make_uint2(lo, hi);
        uint pk = (uint)__builtin_amdgcn_cvt_pk_fp8_f32(v.x, v.y, 0, false);
        pk = (uint)__builtin_amdgcn_cvt_pk_fp8_f32(v.z, v.w, (int)pk, true);
        int node = i >> 5, col4 = i & 31;
        int p = col4 >> 3, q = col4 & 7;
        xf8c[((size_t)p * NN + node) * 8 + q] = pk;
    }
}

// hb (bf16 row-major) -> hf8c (fp8, chunk-major), 8 elements per thread
__global__ void conv_h_kernel(const ushort* __restrict__ hb, uint* __restrict__ hf8c) {
    int i = blockIdx.x * 256 + threadIdx.x;
    if (i < NN * DF / 8) {
        uint4 v = ((const uint4*)hb)[i];
        uint a = (uint)__builtin_amdgcn_cvt_pk_fp8_f32(bf2f_lo(v.x), bf2f_hi(v.x), 0, false);
        a = (uint)__builtin_amdgcn_cvt_pk_fp8_f32(bf2f_lo(v.y), bf2f_hi(v.y), (int)a, true);
        uint b = (uint)__builtin_amdgcn_cvt_pk_fp8_f32(bf2f_lo(v.z), bf2f_hi(v.z), 0, false);
        b = (uint)__builtin_amdgcn_cvt_pk_fp8_f32(bf2f_lo(v.w), bf2f_hi(v.w), (int)b, true);
        int node = i >> 4, col8 = i & 15;
        int p = col8 >> 2, q2 = col8 & 3;
        ((uint2*)hf8c)[((size_t)p * NN + node) * 4 + q2] = make_uint2(a, b);
    }
}

// ---------------------------------------------------------------------------
// W^T build: WT[n][k] (n<128, k<256) = bf16( k<128 ? Wl[k][n] : Wr[k-128][n] )
// ---------------------------------------------------------------------------
__global__ void conv_w_kernel(const float* __restrict__ W1l, const float* __restrict__ W1r,
                              const float* __restrict__ W2l, const float* __restrict__ W2r,
                              ushort* __restrict__ WT1, ushort* __restrict__ WT2) {
    int id = blockIdx.x * 256 + threadIdx.x;
    if (id < 128 * 256) {
        int n = id >> 8, k = id & 255;
        float a = (k < 128) ? W1l[k * 128 + n] : W1r[(k - 128) * 128 + n];
        float b = (k < 128) ? W2l[k * 128 + n] : W2r[(k - 128) * 128 + n];
        WT1[id] = f2bf(a);
        WT2[id] = f2bf(b);
    }
}

// ---------------------------------------------------------------------------
// Mean aggregation, CSR + chunked. One dispatch per 32-column fp8 chunk p:
// working set = NN*32B = 3.2MB -> resident in each XCD's 4MB L2.
// 2 lanes per node, lane reads uint4 (16 fp8 = 16B); unroll x4 -> 4
// outstanding gathers/lane. fp32 accumulate, bf16 output.
// ---------------------------------------------------------------------------
static __device__ __forceinline__ void acc16(floatx2* ac, uint4 v) {
    ac[0] += __builtin_amdgcn_cvt_pk_f32_fp8((int)v.x, false);
    ac[1] += __builtin_amdgcn_cvt_pk_f32_fp8((int)v.x, true);
    ac[2] += __builtin_amdgcn_cvt_pk_f32_fp8((int)v.y, false);
    ac[3] += __builtin_amdgcn_cvt_pk_f32_fp8((int)v.y, true);
    ac[4] += __builtin_amdgcn_cvt_pk_f32_fp8((int)v.z, false);
    ac[5] += __builtin_amdgcn_cvt_pk_f32_fp8((int)v.z, true);
    ac[6] += __builtin_amdgcn_cvt_pk_f32_fp8((int)v.w, false);
    ac[7] += __builtin_amdgcn_cvt_pk_f32_fp8((int)v.w, true);
}

__global__ __launch_bounds__(256) void agg_csr(const uint* __restrict__ feat8,
                                               const int* __restrict__ srt,
                                               const int* __restrict__ off,
                                               ushort* __restrict__ aggb, int p) {
    int n = blockIdx.x * 128 + (threadIdx.x >> 1);
    int l = threadIdx.x & 1;
    if (n >= NN) return;
    // slab p as uint4 rows: 2 uint4 per node row (32B)
    const uint4* f = (const uint4*)(feat8 + (size_t)p * (NN * 8)) + l;

    int beg = off[n];
    int end = (n < NN - 1) ? off[n + 1] : NE;

    floatx2 ac[8];
    #pragma unroll
    for (int t = 0; t < 8; ++t) ac[t] = (floatx2){0.f, 0.f};

    int i = beg;
    for (; i + 4 <= end; i += 4) {
        int i0 = srt[i], i1 = srt[i + 1], i2 = srt[i + 2], i3 = srt[i + 3];
        uint4 v0 = f[(size_t)i0 * 2];
        uint4 v1 = f[(size_t)i1 * 2];
        uint4 v2 = f[(size_t)i2 * 2];
        uint4 v3 = f[(size_t)i3 * 2];
        acc16(ac, v0);
        acc16(ac, v1);
        acc16(ac, v2);
        acc16(ac, v3);
    }
    for (; i < end; ++i) {
        uint4 v = f[(size_t)srt[i] * 2];
        acc16(ac, v);
    }

    float inv = 1.0f / fmaxf((float)(end - beg), 1.0f);
    uint o[8];
    #pragma unroll
    for (int t = 0; t < 8; ++t)
        o[t] = (uint)f2bf(ac[t].x * inv) | ((uint)f2bf(ac[t].y * inv) << 16);
    ushort* dp = aggb + (size_t)n * 128 + p * 32 + l * 16;
    ((uint4*)dp)[0] = make_uint4(o[0], o[1], o[2], o[3]);
    ((uint4*)dp)[1] = make_uint4(o[4], o[5], o[6], o[7]);
}

// ---------------------------------------------------------------------------
// Fused GEMM: C[n,j] = act( [agg|self][n,:] @ WT[j,:] + bias[j] ), K=256.
// 512 threads = 8 waves, 128 rows/block. WT staged in LDS (XOR swizzle, 64KB).
// ---------------------------------------------------------------------------
template <int RELU, int BF16OUT>
__global__ __launch_bounds__(512, 4) void gemm_mfma(
        const ushort* __restrict__ aggb, const ushort* __restrict__ selfb,
        const ushort* __restrict__ WT, const float* __restrict__ bias,
        void* __restrict__ outv) {
    __shared__ ushort sWT[128 * 256];            // 64KB, swizzled chunks
    const int tid = threadIdx.x;
    const int blk = blockIdx.x;

    #pragma unroll
    for (int it = 0; it < 8; ++it) {
        int flat = it * 512 + tid;               // 0..4095
        int col = flat >> 5;
        int c = flat & 31;
        uint4 v = *(const uint4*)(WT + (size_t)col * 256 + c * 8);
        *(uint4*)&sWT[col * 256 + (c ^ (col & 7)) * 8] = v;
    }

    const int w = tid >> 6;
    const int lane = tid & 63;
    const int m = lane & 15;
    const int q = lane >> 4;

    int node_m = blk * 128 + w * 16 + m;
    int cn = node_m < NN ? node_m : NN - 1;
    const ushort* arow = aggb + (size_t)cn * 128;
    const ushort* xrow = selfb + (size_t)cn * 128;
    short8 a[8];
    #pragma unroll
    for (int kk = 0; kk < 4; ++kk) {
        a[kk]     = *(const short8*)(arow + kk * 32 + q * 8);
        a[4 + kk] = *(const short8*)(xrow + kk * 32 + q * 8);
    }

    __syncthreads();

    floatx4 acc[8];
    #pragma unroll
    for (int t = 0; t < 8; ++t) acc[t] = (floatx4){0.f, 0.f, 0.f, 0.f};

    const int m7 = m & 7;
    #pragma unroll
    for (int kk = 0; kk < 8; ++kk) {
        int cx = (kk * 4 + q) ^ m7;
        #pragma unroll
        for (int t = 0; t < 8; ++t) {
            short8 b = *(const short8*)&sWT[(t * 16 + m) * 256 + cx * 8];
            acc[t] = __builtin_amdgcn_mfma_f32_16x16x32_bf16(a[kk], b, acc[t], 0, 0, 0);
        }
    }

    const int node_base = blk * 128 + w * 16 + q * 4;
    #pragma unroll
    for (int t = 0; t < 8; ++t) {
        int col = t * 16 + m;
        float bj = bias[col];
        #pragma unroll
        for (int r = 0; r < 4; ++r) {
            int node = node_base + r;
            if (node < NN) {
                float v = acc[t][r] + bj;
                if (RELU) v = fmaxf(v, 0.0f);
                if (BF16OUT)
                    ((ushort*)outv)[(size_t)node * 128 + col] = f2bf(v);
                else
                    ((float*)outv)[(size_t)node * 128 + col] = v;
            }
        }
    }
}

// ---------------------------------------------------------------------------
extern "C" void kernel_launch(void* const* d_in, const int* in_sizes, int n_in,
                              void* d_out, int out_size, void* d_ws, size_t ws_size,
                              hipStream_t stream) {
    const float* x   = (const float*)d_in[0];
    const int*   ei  = (const int*)d_in[1];
    const float* W1l = (const float*)d_in[2];
    const float* b1  = (const float*)d_in[3];
    const float* W1r = (const float*)d_in[4];
    const float* W2l = (const float*)d_in[5];
    const float* b2  = (const float*)d_in[6];
    const float* W2r = (const float*)d_in[7];
    float*       out = (float*)d_out;

    const int* src = ei;
    const int* dst = ei + NE;

    // workspace layout (bytes), total 96.93 MB
    char* ws = (char*)d_ws;
    int*    off  = (int*)(ws);                   // 400000
    int*    cur  = (int*)(ws + 400000);          // 400000 (also degree counts)
    int*    srt  = (int*)(ws + 800000);          // 6400000 (sorted src)
    ushort* WT1  = (ushort*)(ws + 7200000);      // 65536
    ushort* WT2  = (ushort*)(ws + 7265536);      // 65536
    ushort* xb   = (ushort*)(ws + 7331072);      // 25600000
    uint*   xf8c = (uint*)(ws + 32931072);       // 12800000 (chunk-major fp8)
    ushort* aggb = (ushort*)(ws + 45731072);     // 25600000
    ushort* hb   = (ushort*)(ws + 71331072);     // 25600000 (end 96.93MB)
    uint*   hf8c = xf8c;                         // alias: xf8c dead after agg L1
    int*    bsum = (int*)aggb;                   // alias: used only pre-agg

    // ---- CSR build (once, reused by both layers) ----
    hipMemsetAsync(cur, 0, NN * 4, stream);
    count_deg<<<(NE + 255) / 256, 256, 0, stream>>>(dst, cur);
    k_bsum<<<NB, 1024, 0, stream>>>(cur, bsum);
    k_scan_sums<<<1, 128, 0, stream>>>(bsum);
    k_scan_block<<<NB, 1024, 0, stream>>>(cur, bsum, off, cur);
    k_scatter<<<(NE + 255) / 256, 256, 0, stream>>>(src, dst, cur, srt);

    conv_x_kernel<<<(NN * DF / 4 + 255) / 256, 256, 0, stream>>>(x, xb, xf8c);
    conv_w_kernel<<<128, 256, 0, stream>>>(W1l, W1r, W2l, W2r, WT1, WT2);

    const int gemm_grid = (NN + 127) / 128;
    const int agg_grid = (NN + 127) / 128;

    // ---- layer 1 ----  (4 serialized chunk passes keep each 3.2MB slab L2-hot)
    for (int p = 0; p < 4; ++p)
        agg_csr<<<agg_grid, 256, 0, stream>>>(xf8c, srt, off, aggb, p);
    gemm_mfma<1, 1><<<gemm_grid, 512, 0, stream>>>(aggb, xb, WT1, b1, hb);

    // ---- layer 2 ----
    conv_h_kernel<<<(NN * DF / 8 + 255) / 256, 256, 0, stream>>>(hb, hf8c);
    for (int p = 0; p < 4; ++p)
        agg_csr<<<agg_grid, 256, 0, stream>>>(hf8c, srt, off, aggb, p);
    gemm_mfma<0, 0><<<gemm_grid, 512, 0, stream>>>(aggb, hb, WT2, b2, out);
}

// Round 3
// 410.047 us; speedup vs baseline: 1.0478x; 1.0478x over previous
//
#include <hip/hip_runtime.h>

#define NN 100000
#define NE 1600000
#define DF 128
#define NB 98   // (NN + 1023) / 1024, scan blocks

typedef short short8 __attribute__((ext_vector_type(8)));
typedef float floatx4 __attribute__((ext_vector_type(4)));
typedef float floatx2 __attribute__((ext_vector_type(2)));
typedef unsigned int uint;
typedef unsigned short ushort;

// float -> bf16 (RNE; inputs finite)
static __device__ __forceinline__ ushort f2bf(float f) {
    uint u = __builtin_bit_cast(uint, f);
    return (ushort)((u + 0x7fffu + ((u >> 16) & 1u)) >> 16);
}
static __device__ __forceinline__ float bf2f_lo(uint v) {
    return __builtin_bit_cast(float, v << 16);
}
static __device__ __forceinline__ float bf2f_hi(uint v) {
    return __builtin_bit_cast(float, v & 0xffff0000u);
}

// ---------------------------------------------------------------------------
// CSR build, scatter-free. Random 4B scatters cost 64B/writeback (R1/R2:
// 107MB WRITE_SIZE, 136us). Instead: linked-list chains (coalesced nxt store,
// memory-side atomicExch) + per-node sequential chase-write into srt.
// ---------------------------------------------------------------------------
__global__ void build_ll(const int* __restrict__ dst,
                         int* __restrict__ head, int* __restrict__ nxt) {
    int e = blockIdx.x * blockDim.x + threadIdx.x;
    if (e < NE) {
        int h = dst[e] * 2 + (e & 1);
        nxt[e] = atomicExch(&head[h], e);
    }
}

__global__ void count_deg(const int* __restrict__ dst, int* __restrict__ cnt) {
    int e = blockIdx.x * blockDim.x + threadIdx.x;
    if (e < NE) atomicAdd(&cnt[dst[e]], 1);
}

__global__ __launch_bounds__(1024) void k_bsum(const int* __restrict__ cnt,
                                               int* __restrict__ bsum) {
    __shared__ int s[1024];
    int tid = threadIdx.x;
    int i = blockIdx.x * 1024 + tid;
    s[tid] = (i < NN) ? cnt[i] : 0;
    __syncthreads();
    for (int st = 512; st > 0; st >>= 1) {
        if (tid < st) s[tid] += s[tid + st];
        __syncthreads();
    }
    if (tid == 0) bsum[blockIdx.x] = s[0];
}

__global__ void k_scan_sums(int* bsum) {  // exclusive scan of NB values, 1 block
    __shared__ int s[128];
    int tid = threadIdx.x;
    int v = (tid < NB) ? bsum[tid] : 0;
    s[tid] = v;
    __syncthreads();
    for (int st = 1; st < 128; st <<= 1) {
        int t = (tid >= st) ? s[tid - st] : 0;
        __syncthreads();
        s[tid] += t;
        __syncthreads();
    }
    if (tid < NB) bsum[tid] = s[tid] - v;  // exclusive
}

// exclusive scan within each 1024-block + block offset -> off[i]
__global__ __launch_bounds__(1024) void k_scan_block(const int* __restrict__ cnt,
                                                     const int* __restrict__ bsum,
                                                     int* __restrict__ off) {
    __shared__ int s[2][1024];
    int tid = threadIdx.x;
    int i = blockIdx.x * 1024 + tid;
    int v = (i < NN) ? cnt[i] : 0;
    int b = 0;
    s[0][tid] = v;
    __syncthreads();
    for (int st = 1; st < 1024; st <<= 1) {
        int t = s[b][tid] + ((tid >= st) ? s[b][tid - st] : 0);
        s[b ^ 1][tid] = t;
        __syncthreads();
        b ^= 1;
    }
    int exc = s[b][tid] - v + bsum[blockIdx.x];
    if (i < NN) off[i] = exc;
}

// 2 threads/node: even chain writes forward from off[n], odd chain writes
// backward from off[n+1]-1. The two chains exactly partition the segment
// (order within a segment is irrelevant for mean aggregation). Stores from
// one thread are sequential; adjacent lanes own adjacent segments -> a wave
// writes inside a ~4KB window, lines fully dirtied on one XCD -> no write
// amplification.
__global__ void k_chase(const int* __restrict__ src, const int* __restrict__ head,
                        const int* __restrict__ nxt, const int* __restrict__ off,
                        int* __restrict__ srt) {
    int t = blockIdx.x * blockDim.x + threadIdx.x;
    int n = t >> 1, par = t & 1;
    if (n >= NN) return;
    int c = head[n * 2 + par];
    int pos, step;
    if (par == 0) {
        pos = off[n];
        step = 1;
    } else {
        pos = ((n < NN - 1) ? off[n + 1] : NE) - 1;
        step = -1;
    }
    while (c >= 0) {
        int s = src[c];
        int nx = nxt[c];
        srt[pos] = s;
        pos += step;
        c = nx;
    }
}

// ---------------------------------------------------------------------------
// x (fp32) -> xb (bf16 row-major) + xf8c (fp8 e4m3, CHUNK-MAJOR: 4 slabs of
// 32 fp8 columns; slab p is contiguous NN x 32B -> 3.2 MB, L2-resident)
// ---------------------------------------------------------------------------
__global__ void conv_x_kernel(const float* __restrict__ x, ushort* __restrict__ xb,
                              uint* __restrict__ xf8c) {
    int i = blockIdx.x * 256 + threadIdx.x;
    if (i < NN * DF / 4) {
        float4 v = ((const float4*)x)[i];
        uint lo = (uint)f2bf(v.x) | ((uint)f2bf(v.y) << 16);
        uint hi = (uint)f2bf(v.z) | ((uint)f2bf(v.w) << 16);
        ((uint2*)xb)[i] = make_uint2(lo, hi);
        uint pk = (uint)__builtin_amdgcn_cvt_pk_fp8_f32(v.x, v.y, 0, false);
        pk = (uint)__builtin_amdgcn_cvt_pk_fp8_f32(v.z, v.w, (int)pk, true);
        int node = i >> 5, col4 = i & 31;
        int p = col4 >> 3, q = col4 & 7;
        xf8c[((size_t)p * NN + node) * 8 + q] = pk;
    }
}

// hb (bf16 row-major) -> hf8c (fp8, chunk-major), 8 elements per thread
__global__ void conv_h_kernel(const ushort* __restrict__ hb, uint* __restrict__ hf8c) {
    int i = blockIdx.x * 256 + threadIdx.x;
    if (i < NN * DF / 8) {
        uint4 v = ((const uint4*)hb)[i];
        uint a = (uint)__builtin_amdgcn_cvt_pk_fp8_f32(bf2f_lo(v.x), bf2f_hi(v.x), 0, false);
        a = (uint)__builtin_amdgcn_cvt_pk_fp8_f32(bf2f_lo(v.y), bf2f_hi(v.y), (int)a, true);
        uint b = (uint)__builtin_amdgcn_cvt_pk_fp8_f32(bf2f_lo(v.z), bf2f_hi(v.z), 0, false);
        b = (uint)__builtin_amdgcn_cvt_pk_fp8_f32(bf2f_lo(v.w), bf2f_hi(v.w), (int)b, true);
        int node = i >> 4, col8 = i & 15;
        int p = col8 >> 2, q2 = col8 & 3;
        ((uint2*)hf8c)[((size_t)p * NN + node) * 4 + q2] = make_uint2(a, b);
    }
}

// ---------------------------------------------------------------------------
// W^T build: WT[n][k] (n<128, k<256) = bf16( k<128 ? Wl[k][n] : Wr[k-128][n] )
// ---------------------------------------------------------------------------
__global__ void conv_w_kernel(const float* __restrict__ W1l, const float* __restrict__ W1r,
                              const float* __restrict__ W2l, const float* __restrict__ W2r,
                              ushort* __restrict__ WT1, ushort* __restrict__ WT2) {
    int id = blockIdx.x * 256 + threadIdx.x;
    if (id < 128 * 256) {
        int n = id >> 8, k = id & 255;
        float a = (k < 128) ? W1l[k * 128 + n] : W1r[(k - 128) * 128 + n];
        float b = (k < 128) ? W2l[k * 128 + n] : W2r[(k - 128) * 128 + n];
        WT1[id] = f2bf(a);
        WT2[id] = f2bf(b);
    }
}

// ---------------------------------------------------------------------------
// Mean aggregation, CSR + chunked. One dispatch per 32-column fp8 chunk p:
// working set = NN*32B = 3.2MB -> resident in each XCD's 4MB L2.
// 4 lanes per node, lane reads uint2 (8 fp8); loads independent, unrolled x4.
// ---------------------------------------------------------------------------
static __device__ __forceinline__ void acc8(floatx2* ac, uint2 v) {
    ac[0] += __builtin_amdgcn_cvt_pk_f32_fp8((int)v.x, false);
    ac[1] += __builtin_amdgcn_cvt_pk_f32_fp8((int)v.x, true);
    ac[2] += __builtin_amdgcn_cvt_pk_f32_fp8((int)v.y, false);
    ac[3] += __builtin_amdgcn_cvt_pk_f32_fp8((int)v.y, true);
}

__global__ __launch_bounds__(256) void agg_csr(const uint* __restrict__ feat8,
                                               const int* __restrict__ srt,
                                               const int* __restrict__ off,
                                               ushort* __restrict__ aggb, int p) {
    int n = blockIdx.x * 64 + (threadIdx.x >> 2);
    int l = threadIdx.x & 2;
    if (n >= NN) return;
    const uint2* f = (const uint2*)(feat8 + (size_t)p * (NN * 8)) + (threadIdx.x & 3);

    int beg = off[n];
    int end = (n < NN - 1) ? off[n + 1] : NE;

    floatx2 ac[4];
    #pragma unroll
    for (int t = 0; t < 4; ++t) ac[t] = (floatx2){0.f, 0.f};

    int i = beg;
    for (; i + 4 <= end; i += 4) {
        int i0 = srt[i], i1 = srt[i + 1], i2 = srt[i + 2], i3 = srt[i + 3];
        uint2 v0 = f[(size_t)i0 * 4];
        uint2 v1 = f[(size_t)i1 * 4];
        uint2 v2 = f[(size_t)i2 * 4];
        uint2 v3 = f[(size_t)i3 * 4];
        acc8(ac, v0);
        acc8(ac, v1);
        acc8(ac, v2);
        acc8(ac, v3);
    }
    for (; i < end; ++i) {
        uint2 v = f[(size_t)srt[i] * 4];
        acc8(ac, v);
    }

    float inv = 1.0f / fmaxf((float)(end - beg), 1.0f);
    uint o[4];
    #pragma unroll
    for (int t = 0; t < 4; ++t)
        o[t] = (uint)f2bf(ac[t].x * inv) | ((uint)f2bf(ac[t].y * inv) << 16);
    *(uint4*)(aggb + (size_t)n * 128 + p * 32 + (threadIdx.x & 3) * 8) =
        make_uint4(o[0], o[1], o[2], o[3]);
    (void)l;
}

// ---------------------------------------------------------------------------
// Fused GEMM: C[n,j] = act( [agg|self][n,:] @ WT[j,:] + bias[j] ), K=256.
// 512 threads = 8 waves, 128 rows/block. WT staged in LDS (XOR swizzle, 64KB).
// ---------------------------------------------------------------------------
template <int RELU, int BF16OUT>
__global__ __launch_bounds__(512, 4) void gemm_mfma(
        const ushort* __restrict__ aggb, const ushort* __restrict__ selfb,
        const ushort* __restrict__ WT, const float* __restrict__ bias,
        void* __restrict__ outv) {
    __shared__ ushort sWT[128 * 256];            // 64KB, swizzled chunks
    const int tid = threadIdx.x;
    const int blk = blockIdx.x;

    #pragma unroll
    for (int it = 0; it < 8; ++it) {
        int flat = it * 512 + tid;               // 0..4095
        int col = flat >> 5;
        int c = flat & 31;
        uint4 v = *(const uint4*)(WT + (size_t)col * 256 + c * 8);
        *(uint4*)&sWT[col * 256 + (c ^ (col & 7)) * 8] = v;
    }

    const int w = tid >> 6;
    const int lane = tid & 63;
    const int m = lane & 15;
    const int q = lane >> 4;

    int node_m = blk * 128 + w * 16 + m;
    int cn = node_m < NN ? node_m : NN - 1;
    const ushort* arow = aggb + (size_t)cn * 128;
    const ushort* xrow = selfb + (size_t)cn * 128;
    short8 a[8];
    #pragma unroll
    for (int kk = 0; kk < 4; ++kk) {
        a[kk]     = *(const short8*)(arow + kk * 32 + q * 8);
        a[4 + kk] = *(const short8*)(xrow + kk * 32 + q * 8);
    }

    __syncthreads();

    floatx4 acc[8];
    #pragma unroll
    for (int t = 0; t < 8; ++t) acc[t] = (floatx4){0.f, 0.f, 0.f, 0.f};

    const int m7 = m & 7;
    #pragma unroll
    for (int kk = 0; kk < 8; ++kk) {
        int cx = (kk * 4 + q) ^ m7;
        #pragma unroll
        for (int t = 0; t < 8; ++t) {
            short8 b = *(const short8*)&sWT[(t * 16 + m) * 256 + cx * 8];
            acc[t] = __builtin_amdgcn_mfma_f32_16x16x32_bf16(a[kk], b, acc[t], 0, 0, 0);
        }
    }

    const int node_base = blk * 128 + w * 16 + q * 4;
    #pragma unroll
    for (int t = 0; t < 8; ++t) {
        int col = t * 16 + m;
        float bj = bias[col];
        #pragma unroll
        for (int r = 0; r < 4; ++r) {
            int node = node_base + r;
            if (node < NN) {
                float v = acc[t][r] + bj;
                if (RELU) v = fmaxf(v, 0.0f);
                if (BF16OUT)
                    ((ushort*)outv)[(size_t)node * 128 + col] = f2bf(v);
                else
                    ((float*)outv)[(size_t)node * 128 + col] = v;
            }
        }
    }
}

// ---------------------------------------------------------------------------
extern "C" void kernel_launch(void* const* d_in, const int* in_sizes, int n_in,
                              void* d_out, int out_size, void* d_ws, size_t ws_size,
                              hipStream_t stream) {
    const float* x   = (const float*)d_in[0];
    const int*   ei  = (const int*)d_in[1];
    const float* W1l = (const float*)d_in[2];
    const float* b1  = (const float*)d_in[3];
    const float* W1r = (const float*)d_in[4];
    const float* W2l = (const float*)d_in[5];
    const float* b2  = (const float*)d_in[6];
    const float* W2r = (const float*)d_in[7];
    float*       out = (float*)d_out;

    const int* src = ei;
    const int* dst = ei + NE;

    // workspace layout (bytes), total 96.93 MB
    char* ws = (char*)d_ws;
    int*    off  = (int*)(ws);                   // 400000
    int*    srt  = (int*)(ws + 400000);          // 6400000 (ends 6.8MB)
    ushort* WT1  = (ushort*)(ws + 7200000);      // 65536
    ushort* WT2  = (ushort*)(ws + 7265536);      // 65536
    ushort* xb   = (ushort*)(ws + 7331072);      // 25600000
    uint*   xf8c = (uint*)(ws + 32931072);       // 12800000 (chunk-major fp8)
    ushort* aggb = (ushort*)(ws + 45731072);     // 25600000
    ushort* hb   = (ushort*)(ws + 71331072);     // 25600000 (end 96.93MB)
    uint*   hf8c = xf8c;                         // alias: xf8c dead after agg L1
    // CSR-build temporaries, all dead before aggb is written:
    int*    nxt  = (int*)aggb;                   // 6400000
    int*    bsum = (int*)((char*)aggb + 6400000);       // 392
    int*    head = (int*)((char*)aggb + 6400512);       // 800000
    int*    cnt  = (int*)((char*)aggb + 7200512);       // 400000

    // ---- CSR build (scatter-free; reused by both layers) ----
    hipMemsetAsync(head, 0xFF, 800000, stream);  // heads = -1
    hipMemsetAsync(cnt, 0, 400000, stream);
    build_ll<<<(NE + 255) / 256, 256, 0, stream>>>(dst, head, nxt);
    count_deg<<<(NE + 255) / 256, 256, 0, stream>>>(dst, cnt);
    k_bsum<<<NB, 1024, 0, stream>>>(cnt, bsum);
    k_scan_sums<<<1, 128, 0, stream>>>(bsum);
    k_scan_block<<<NB, 1024, 0, stream>>>(cnt, bsum, off);
    k_chase<<<(2 * NN + 255) / 256, 256, 0, stream>>>(src, head, nxt, off, srt);

    conv_x_kernel<<<(NN * DF / 4 + 255) / 256, 256, 0, stream>>>(x, xb, xf8c);
    conv_w_kernel<<<128, 256, 0, stream>>>(W1l, W1r, W2l, W2r, WT1, WT2);

    const int gemm_grid = (NN + 127) / 128;
    const int agg_grid = (NN + 63) / 64;

    // ---- layer 1 ----  (4 serialized chunk passes keep each 3.2MB slab L2-hot)
    for (int p = 0; p < 4; ++p)
        agg_csr<<<agg_grid, 256, 0, stream>>>(xf8c, srt, off, aggb, p);
    gemm_mfma<1, 1><<<gemm_grid, 512, 0, stream>>>(aggb, xb, WT1, b1, hb);

    // ---- layer 2 ----
    conv_h_kernel<<<(NN * DF / 8 + 255) / 256, 256, 0, stream>>>(hb, hf8c);
    for (int p = 0; p < 4; ++p)
        agg_csr<<<agg_grid, 256, 0, stream>>>(hf8c, srt, off, aggb, p);
    gemm_mfma<0, 0><<<gemm_grid, 512, 0, stream>>>(aggb, hb, WT2, b2, out);
}

// Round 4
// 264.204 us; speedup vs baseline: 1.6262x; 1.5520x over previous
//
#include <hip/hip_runtime.h>

#define NN 100000
#define NE 1600000
#define DF 128
#define NBUCK 391     // ceil(NN/256); bucket b = dst >> 8
#define PB_BLOCKS 196 // ceil(NE / 8192)

typedef short short8 __attribute__((ext_vector_type(8)));
typedef float floatx4 __attribute__((ext_vector_type(4)));
typedef float floatx2 __attribute__((ext_vector_type(2)));
typedef unsigned int uint;
typedef unsigned short ushort;

// float -> bf16 (RNE; inputs finite)
static __device__ __forceinline__ ushort f2bf(float f) {
    uint u = __builtin_bit_cast(uint, f);
    return (ushort)((u + 0x7fffu + ((u >> 16) & 1u)) >> 16);
}
static __device__ __forceinline__ float bf2f_lo(uint v) {
    return __builtin_bit_cast(float, v << 16);
}
static __device__ __forceinline__ float bf2f_hi(uint v) {
    return __builtin_bit_cast(float, v & 0xffff0000u);
}

// ---------------------------------------------------------------------------
// CSR build via bucketed counting sort. Lesson from R1-R3: any plan that
// issues 1.6M random fine-grained memory ops (scatter stores 107MB, atomicExch
// 56MB, chase reads) costs 60-140us. Here every global access is coalesced or
// confined to a per-block L2-resident window; the only global atomics are
// 77K block-aggregated ones.
// ---------------------------------------------------------------------------

// Pass A: bucket histogram (LDS-aggregated).
__global__ __launch_bounds__(512) void pA_hist(const int* __restrict__ dst,
                                               int* __restrict__ gcnt) {
    __shared__ int h[NBUCK];
    for (int i = threadIdx.x; i < NBUCK; i += 512) h[i] = 0;
    __syncthreads();
    int eb = blockIdx.x * 8192 + threadIdx.x;
    #pragma unroll
    for (int k = 0; k < 16; ++k) {
        int e = eb + k * 512;
        if (e < NE) atomicAdd(&h[dst[e] >> 8], 1);
    }
    __syncthreads();
    for (int i = threadIdx.x; i < NBUCK; i += 512)
        if (h[i]) atomicAdd(&gcnt[i], h[i]);
}

// Pass S: exclusive scan of bucket counts -> goff (bucket base in srt); gcur=goff.
__global__ __launch_bounds__(512) void pS_scan(const int* __restrict__ gcnt,
                                               int* __restrict__ goff,
                                               int* __restrict__ gcur) {
    __shared__ int s[512];
    int tid = threadIdx.x;
    int v = (tid < NBUCK) ? gcnt[tid] : 0;
    s[tid] = v;
    __syncthreads();
    for (int st = 1; st < 512; st <<= 1) {
        int t = (tid >= st) ? s[tid - st] : 0;
        __syncthreads();
        s[tid] += t;
        __syncthreads();
    }
    if (tid < NBUCK) {
        int e = s[tid] - v;
        goff[tid] = e;
        gcur[tid] = e;
    }
    if (tid == 0) goff[NBUCK] = NE;
}

// Pass B: partition (src,dst) pairs bucket-contiguous. Per-block LDS ranks;
// one global atomicAdd per (block,bucket). Writes land in ~170B runs.
__global__ __launch_bounds__(512) void pB_part(const int* __restrict__ src,
                                               const int* __restrict__ dst,
                                               int* __restrict__ gcur,
                                               uint2* __restrict__ pairs) {
    __shared__ int h[NBUCK];
    __shared__ int base[NBUCK];
    for (int i = threadIdx.x; i < NBUCK; i += 512) h[i] = 0;
    __syncthreads();
    int eb = blockIdx.x * 8192 + threadIdx.x;
    int bkt[16], dv[16];
    #pragma unroll
    for (int k = 0; k < 16; ++k) {
        int e = eb + k * 512;
        bkt[k] = -1;
        if (e < NE) {
            int d = dst[e];
            dv[k] = d;
            bkt[k] = d >> 8;
            atomicAdd(&h[bkt[k]], 1);
        }
    }
    __syncthreads();
    for (int i = threadIdx.x; i < NBUCK; i += 512) {
        base[i] = h[i] ? atomicAdd(&gcur[i], h[i]) : 0;
        h[i] = 0;
    }
    __syncthreads();
    #pragma unroll
    for (int k = 0; k < 16; ++k) {
        int e = eb + k * 512;
        if (e < NE) {
            int r = atomicAdd(&h[bkt[k]], 1);
            pairs[base[bkt[k]] + r] = make_uint2((uint)src[e], (uint)dv[k]);
        }
    }
}

// Pass C: one block per bucket. LDS degree count + scan -> off[] (coalesced),
// then scatter src into the bucket's ~16KB srt window (single-XCD dirtying,
// no write amplification). Second pairs read is L2-hot.
__global__ __launch_bounds__(256) void pC_scatter(const uint2* __restrict__ pairs,
                                                  const int* __restrict__ goff,
                                                  int* __restrict__ off,
                                                  int* __restrict__ srt) {
    __shared__ int deg[256];
    __shared__ int loc[256];
    int b = blockIdx.x;
    int beg = goff[b], end = goff[b + 1];
    int tid = threadIdx.x;
    deg[tid] = 0;
    __syncthreads();
    for (int i = beg + tid; i < end; i += 256)
        atomicAdd(&deg[pairs[i].y & 255], 1);
    __syncthreads();
    int v = deg[tid];
    loc[tid] = v;
    __syncthreads();
    for (int st = 1; st < 256; st <<= 1) {
        int t = (tid >= st) ? loc[tid - st] : 0;
        __syncthreads();
        loc[tid] += t;
        __syncthreads();
    }
    int excl = loc[tid] - v + beg;     // global CSR offset for node (b<<8)+tid
    int n = (b << 8) + tid;
    if (n < NN) off[n] = excl;
    __syncthreads();
    deg[tid] = excl;                   // reuse as cursor
    __syncthreads();
    for (int i = beg + tid; i < end; i += 256) {
        uint2 pr = pairs[i];
        int pos = atomicAdd(&deg[pr.y & 255], 1);
        srt[pos] = (int)pr.x;
    }
}

// ---------------------------------------------------------------------------
// x (fp32) -> xb (bf16 row-major) + xf8c (fp8 e4m3, CHUNK-MAJOR: 4 slabs of
// 32 fp8 columns; slab p is contiguous NN x 32B -> 3.2 MB, L2-resident)
// ---------------------------------------------------------------------------
__global__ void conv_x_kernel(const float* __restrict__ x, ushort* __restrict__ xb,
                              uint* __restrict__ xf8c) {
    int i = blockIdx.x * 256 + threadIdx.x;
    if (i < NN * DF / 4) {
        float4 v = ((const float4*)x)[i];
        uint lo = (uint)f2bf(v.x) | ((uint)f2bf(v.y) << 16);
        uint hi = (uint)f2bf(v.z) | ((uint)f2bf(v.w) << 16);
        ((uint2*)xb)[i] = make_uint2(lo, hi);
        uint pk = (uint)__builtin_amdgcn_cvt_pk_fp8_f32(v.x, v.y, 0, false);
        pk = (uint)__builtin_amdgcn_cvt_pk_fp8_f32(v.z, v.w, (int)pk, true);
        int node = i >> 5, col4 = i & 31;
        int p = col4 >> 3, q = col4 & 7;
        xf8c[((size_t)p * NN + node) * 8 + q] = pk;
    }
}

// hb (bf16 row-major) -> hf8c (fp8, chunk-major), 8 elements per thread
__global__ void conv_h_kernel(const ushort* __restrict__ hb, uint* __restrict__ hf8c) {
    int i = blockIdx.x * 256 + threadIdx.x;
    if (i < NN * DF / 8) {
        uint4 v = ((const uint4*)hb)[i];
        uint a = (uint)__builtin_amdgcn_cvt_pk_fp8_f32(bf2f_lo(v.x), bf2f_hi(v.x), 0, false);
        a = (uint)__builtin_amdgcn_cvt_pk_fp8_f32(bf2f_lo(v.y), bf2f_hi(v.y), (int)a, true);
        uint b = (uint)__builtin_amdgcn_cvt_pk_fp8_f32(bf2f_lo(v.z), bf2f_hi(v.z), 0, false);
        b = (uint)__builtin_amdgcn_cvt_pk_fp8_f32(bf2f_lo(v.w), bf2f_hi(v.w), (int)b, true);
        int node = i >> 4, col8 = i & 15;
        int p = col8 >> 2, q2 = col8 & 3;
        ((uint2*)hf8c)[((size_t)p * NN + node) * 4 + q2] = make_uint2(a, b);
    }
}

// ---------------------------------------------------------------------------
// W^T build: WT[n][k] (n<128, k<256) = bf16( k<128 ? Wl[k][n] : Wr[k-128][n] )
// ---------------------------------------------------------------------------
__global__ void conv_w_kernel(const float* __restrict__ W1l, const float* __restrict__ W1r,
                              const float* __restrict__ W2l, const float* __restrict__ W2r,
                              ushort* __restrict__ WT1, ushort* __restrict__ WT2) {
    int id = blockIdx.x * 256 + threadIdx.x;
    if (id < 128 * 256) {
        int n = id >> 8, k = id & 255;
        float a = (k < 128) ? W1l[k * 128 + n] : W1r[(k - 128) * 128 + n];
        float b = (k < 128) ? W2l[k * 128 + n] : W2r[(k - 128) * 128 + n];
        WT1[id] = f2bf(a);
        WT2[id] = f2bf(b);
    }
}

// ---------------------------------------------------------------------------
// Mean aggregation, CSR + chunked. One dispatch per 32-column fp8 chunk p:
// working set = NN*32B = 3.2MB -> resident in each XCD's 4MB L2.
// 4 lanes per node, lane reads uint2 (8 fp8); loads independent, unrolled x4.
// ---------------------------------------------------------------------------
static __device__ __forceinline__ void acc8(floatx2* ac, uint2 v) {
    ac[0] += __builtin_amdgcn_cvt_pk_f32_fp8((int)v.x, false);
    ac[1] += __builtin_amdgcn_cvt_pk_f32_fp8((int)v.x, true);
    ac[2] += __builtin_amdgcn_cvt_pk_f32_fp8((int)v.y, false);
    ac[3] += __builtin_amdgcn_cvt_pk_f32_fp8((int)v.y, true);
}

__global__ __launch_bounds__(256) void agg_csr(const uint* __restrict__ feat8,
                                               const int* __restrict__ srt,
                                               const int* __restrict__ off,
                                               ushort* __restrict__ aggb, int p) {
    int n = blockIdx.x * 64 + (threadIdx.x >> 2);
    int l = threadIdx.x & 3;
    if (n >= NN) return;
    const uint2* f = (const uint2*)(feat8 + (size_t)p * (NN * 8)) + l;

    int beg = off[n];
    int end = (n < NN - 1) ? off[n + 1] : NE;

    floatx2 ac[4];
    #pragma unroll
    for (int t = 0; t < 4; ++t) ac[t] = (floatx2){0.f, 0.f};

    int i = beg;
    for (; i + 4 <= end; i += 4) {
        int i0 = srt[i], i1 = srt[i + 1], i2 = srt[i + 2], i3 = srt[i + 3];
        uint2 v0 = f[(size_t)i0 * 4];
        uint2 v1 = f[(size_t)i1 * 4];
        uint2 v2 = f[(size_t)i2 * 4];
        uint2 v3 = f[(size_t)i3 * 4];
        acc8(ac, v0);
        acc8(ac, v1);
        acc8(ac, v2);
        acc8(ac, v3);
    }
    for (; i < end; ++i) {
        uint2 v = f[(size_t)srt[i] * 4];
        acc8(ac, v);
    }

    float inv = 1.0f / fmaxf((float)(end - beg), 1.0f);
    uint o[4];
    #pragma unroll
    for (int t = 0; t < 4; ++t)
        o[t] = (uint)f2bf(ac[t].x * inv) | ((uint)f2bf(ac[t].y * inv) << 16);
    *(uint4*)(aggb + (size_t)n * 128 + p * 32 + l * 8) =
        make_uint4(o[0], o[1], o[2], o[3]);
}

// ---------------------------------------------------------------------------
// Fused GEMM: C[n,j] = act( [agg|self][n,:] @ WT[j,:] + bias[j] ), K=256.
// 512 threads = 8 waves, 128 rows/block. WT staged in LDS (XOR swizzle, 64KB).
// ---------------------------------------------------------------------------
template <int RELU, int BF16OUT>
__global__ __launch_bounds__(512, 4) void gemm_mfma(
        const ushort* __restrict__ aggb, const ushort* __restrict__ selfb,
        const ushort* __restrict__ WT, const float* __restrict__ bias,
        void* __restrict__ outv) {
    __shared__ ushort sWT[128 * 256];            // 64KB, swizzled chunks
    const int tid = threadIdx.x;
    const int blk = blockIdx.x;

    #pragma unroll
    for (int it = 0; it < 8; ++it) {
        int flat = it * 512 + tid;               // 0..4095
        int col = flat >> 5;
        int c = flat & 31;
        uint4 v = *(const uint4*)(WT + (size_t)col * 256 + c * 8);
        *(uint4*)&sWT[col * 256 + (c ^ (col & 7)) * 8] = v;
    }

    const int w = tid >> 6;
    const int lane = tid & 63;
    const int m = lane & 15;
    const int q = lane >> 4;

    int node_m = blk * 128 + w * 16 + m;
    int cn = node_m < NN ? node_m : NN - 1;
    const ushort* arow = aggb + (size_t)cn * 128;
    const ushort* xrow = selfb + (size_t)cn * 128;
    short8 a[8];
    #pragma unroll
    for (int kk = 0; kk < 4; ++kk) {
        a[kk]     = *(const short8*)(arow + kk * 32 + q * 8);
        a[4 + kk] = *(const short8*)(xrow + kk * 32 + q * 8);
    }

    __syncthreads();

    floatx4 acc[8];
    #pragma unroll
    for (int t = 0; t < 8; ++t) acc[t] = (floatx4){0.f, 0.f, 0.f, 0.f};

    const int m7 = m & 7;
    #pragma unroll
    for (int kk = 0; kk < 8; ++kk) {
        int cx = (kk * 4 + q) ^ m7;
        #pragma unroll
        for (int t = 0; t < 8; ++t) {
            short8 b = *(const short8*)&sWT[(t * 16 + m) * 256 + cx * 8];
            acc[t] = __builtin_amdgcn_mfma_f32_16x16x32_bf16(a[kk], b, acc[t], 0, 0, 0);
        }
    }

    const int node_base = blk * 128 + w * 16 + q * 4;
    #pragma unroll
    for (int t = 0; t < 8; ++t) {
        int col = t * 16 + m;
        float bj = bias[col];
        #pragma unroll
        for (int r = 0; r < 4; ++r) {
            int node = node_base + r;
            if (node < NN) {
                float v = acc[t][r] + bj;
                if (RELU) v = fmaxf(v, 0.0f);
                if (BF16OUT)
                    ((ushort*)outv)[(size_t)node * 128 + col] = f2bf(v);
                else
                    ((float*)outv)[(size_t)node * 128 + col] = v;
            }
        }
    }
}

// ---------------------------------------------------------------------------
extern "C" void kernel_launch(void* const* d_in, const int* in_sizes, int n_in,
                              void* d_out, int out_size, void* d_ws, size_t ws_size,
                              hipStream_t stream) {
    const float* x   = (const float*)d_in[0];
    const int*   ei  = (const int*)d_in[1];
    const float* W1l = (const float*)d_in[2];
    const float* b1  = (const float*)d_in[3];
    const float* W1r = (const float*)d_in[4];
    const float* W2l = (const float*)d_in[5];
    const float* b2  = (const float*)d_in[6];
    const float* W2r = (const float*)d_in[7];
    float*       out = (float*)d_out;

    const int* src = ei;
    const int* dst = ei + NE;

    // workspace layout (bytes), total 96.93 MB
    char* ws = (char*)d_ws;
    int*    off  = (int*)(ws);                   // 400000
    int*    srt  = (int*)(ws + 400000);          // 6400000 (ends 6.8MB)
    ushort* WT1  = (ushort*)(ws + 7200000);      // 65536
    ushort* WT2  = (ushort*)(ws + 7265536);      // 65536
    ushort* xb   = (ushort*)(ws + 7331072);      // 25600000
    uint*   xf8c = (uint*)(ws + 32931072);       // 12800000 (chunk-major fp8)
    ushort* aggb = (ushort*)(ws + 45731072);     // 25600000
    ushort* hb   = (ushort*)(ws + 71331072);     // 25600000 (end 96.93MB)
    uint*   hf8c = xf8c;                         // alias: xf8c dead after agg L1
    // CSR-build temporaries, all dead before aggb is written:
    uint2*  pairs = (uint2*)aggb;                       // 12800000
    int*    gcnt  = (int*)((char*)aggb + 12800000);     // 1564
    int*    goff  = (int*)((char*)aggb + 12801600);     // 1568
    int*    gcur  = (int*)((char*)aggb + 12803200);     // 1564

    // ---- CSR build: bucketed counting sort (no random fine-grained ops) ----
    hipMemsetAsync(gcnt, 0, NBUCK * 4, stream);
    pA_hist<<<PB_BLOCKS, 512, 0, stream>>>(dst, gcnt);
    pS_scan<<<1, 512, 0, stream>>>(gcnt, goff, gcur);
    pB_part<<<PB_BLOCKS, 512, 0, stream>>>(src, dst, gcur, pairs);
    pC_scatter<<<NBUCK, 256, 0, stream>>>(pairs, goff, off, srt);

    conv_x_kernel<<<(NN * DF / 4 + 255) / 256, 256, 0, stream>>>(x, xb, xf8c);
    conv_w_kernel<<<128, 256, 0, stream>>>(W1l, W1r, W2l, W2r, WT1, WT2);

    const int gemm_grid = (NN + 127) / 128;
    const int agg_grid = (NN + 63) / 64;

    // ---- layer 1 ----  (4 serialized chunk passes keep each 3.2MB slab L2-hot)
    for (int p = 0; p < 4; ++p)
        agg_csr<<<agg_grid, 256, 0, stream>>>(xf8c, srt, off, aggb, p);
    gemm_mfma<1, 1><<<gemm_grid, 512, 0, stream>>>(aggb, xb, WT1, b1, hb);

    // ---- layer 2 ----
    conv_h_kernel<<<(NN * DF / 8 + 255) / 256, 256, 0, stream>>>(hb, hf8c);
    for (int p = 0; p < 4; ++p)
        agg_csr<<<agg_grid, 256, 0, stream>>>(hf8c, srt, off, aggb, p);
    gemm_mfma<0, 0><<<gemm_grid, 512, 0, stream>>>(aggb, hb, WT2, b2, out);
}

// Round 6
// 259.769 us; speedup vs baseline: 1.6539x; 1.0171x over previous
//
#include <hip/hip_runtime.h>

#define NN 100000
#define NE 1600000
#define DF 128
#define NBUCK 391     // ceil(NN/256); bucket b = dst >> 8
#define PB_BLOCKS 196 // ceil(NE / 8192)
#define CX_BLOCKS 12500
#define CW_BLOCKS 128

typedef short short8 __attribute__((ext_vector_type(8)));
typedef float floatx4 __attribute__((ext_vector_type(4)));
typedef float floatx2 __attribute__((ext_vector_type(2)));
typedef unsigned int uintx4 __attribute__((ext_vector_type(4)));
typedef unsigned int uint;
typedef unsigned short ushort;
typedef unsigned char uchar;

// float -> bf16 (RNE; inputs finite)
static __device__ __forceinline__ ushort f2bf(float f) {
    uint u = __builtin_bit_cast(uint, f);
    return (ushort)((u + 0x7fffu + ((u >> 16) & 1u)) >> 16);
}

// ---------------------------------------------------------------------------
// Fused pre-pass: three independent jobs in one dispatch (block-range split)
//   [0, CX)        conv_x: x fp32 -> xb bf16 + xf8c fp8 chunk-major
//   [CX, CX+CW)    conv_w: W^T bf16 build
//   [CX+CW, ...)   pA: bucket histogram (LDS-aggregated)
// ---------------------------------------------------------------------------
__global__ __launch_bounds__(256) void fused_pre(
        const float* __restrict__ x, ushort* __restrict__ xb, uint* __restrict__ xf8c,
        const float* __restrict__ W1l, const float* __restrict__ W1r,
        const float* __restrict__ W2l, const float* __restrict__ W2r,
        ushort* __restrict__ WT1, ushort* __restrict__ WT2,
        const int* __restrict__ dst, int* __restrict__ gcnt) {
    __shared__ int h[NBUCK];
    int bid = blockIdx.x;
    int tid = threadIdx.x;
    if (bid < CX_BLOCKS) {
        int i = bid * 256 + tid;
        if (i < NN * DF / 4) {
            float4 v = ((const float4*)x)[i];
            uint lo = (uint)f2bf(v.x) | ((uint)f2bf(v.y) << 16);
            uint hi = (uint)f2bf(v.z) | ((uint)f2bf(v.w) << 16);
            ((uint2*)xb)[i] = make_uint2(lo, hi);
            uint pk = (uint)__builtin_amdgcn_cvt_pk_fp8_f32(v.x, v.y, 0, false);
            pk = (uint)__builtin_amdgcn_cvt_pk_fp8_f32(v.z, v.w, (int)pk, true);
            int node = i >> 5, col4 = i & 31;
            int p = col4 >> 3, q = col4 & 7;
            xf8c[((size_t)p * NN + node) * 8 + q] = pk;
        }
    } else if (bid < CX_BLOCKS + CW_BLOCKS) {
        int id = (bid - CX_BLOCKS) * 256 + tid;
        int n = id >> 8, k = id & 255;
        float a = (k < 128) ? W1l[k * 128 + n] : W1r[(k - 128) * 128 + n];
        float b = (k < 128) ? W2l[k * 128 + n] : W2r[(k - 128) * 128 + n];
        WT1[id] = f2bf(a);
        WT2[id] = f2bf(b);
    } else {
        int blk = bid - CX_BLOCKS - CW_BLOCKS;
        for (int i = tid; i < NBUCK; i += 256) h[i] = 0;
        __syncthreads();
        int eb = blk * 8192 + tid;
        #pragma unroll
        for (int k = 0; k < 32; ++k) {
            int e = eb + k * 256;
            if (e < NE) atomicAdd(&h[dst[e] >> 8], 1);
        }
        __syncthreads();
        for (int i = tid; i < NBUCK; i += 256)
            if (h[i]) atomicAdd(&gcnt[i], h[i]);
    }
}

// Pass S: exclusive scan of bucket counts -> goff (bucket base in srt); gcur=goff.
__global__ __launch_bounds__(512) void pS_scan(const int* __restrict__ gcnt,
                                               int* __restrict__ goff,
                                               int* __restrict__ gcur) {
    __shared__ int s[512];
    int tid = threadIdx.x;
    int v = (tid < NBUCK) ? gcnt[tid] : 0;
    s[tid] = v;
    __syncthreads();
    for (int st = 1; st < 512; st <<= 1) {
        int t = (tid >= st) ? s[tid - st] : 0;
        __syncthreads();
        s[tid] += t;
        __syncthreads();
    }
    if (tid < NBUCK) {
        int e = s[tid] - v;
        goff[tid] = e;
        gcur[tid] = e;
    }
    if (tid == 0) goff[NBUCK] = NE;
}

// Pass B: partition (src,dst) pairs bucket-contiguous. Per-block LDS ranks;
// one global atomicAdd per (block,bucket). Writes land in ~170B runs.
__global__ __launch_bounds__(512) void pB_part(const int* __restrict__ src,
                                               const int* __restrict__ dst,
                                               int* __restrict__ gcur,
                                               uint2* __restrict__ pairs) {
    __shared__ int h[NBUCK];
    __shared__ int base[NBUCK];
    for (int i = threadIdx.x; i < NBUCK; i += 512) h[i] = 0;
    __syncthreads();
    int eb = blockIdx.x * 8192 + threadIdx.x;
    int bkt[16], dv[16];
    #pragma unroll
    for (int k = 0; k < 16; ++k) {
        int e = eb + k * 512;
        bkt[k] = -1;
        if (e < NE) {
            int d = dst[e];
            dv[k] = d;
            bkt[k] = d >> 8;
            atomicAdd(&h[bkt[k]], 1);
        }
    }
    __syncthreads();
    for (int i = threadIdx.x; i < NBUCK; i += 512) {
        base[i] = h[i] ? atomicAdd(&gcur[i], h[i]) : 0;
        h[i] = 0;
    }
    __syncthreads();
    #pragma unroll
    for (int k = 0; k < 16; ++k) {
        int e = eb + k * 512;
        if (e < NE) {
            int r = atomicAdd(&h[bkt[k]], 1);
            pairs[base[bkt[k]] + r] = make_uint2((uint)src[e], (uint)dv[k]);
        }
    }
}

// Pass C: one block per bucket. LDS degree count + scan -> off[] (coalesced),
// then scatter src into the bucket's ~16KB srt window (single-XCD dirtying,
// no write amplification). Second pairs read is L2-hot.
__global__ __launch_bounds__(256) void pC_scatter(const uint2* __restrict__ pairs,
                                                  const int* __restrict__ goff,
                                                  int* __restrict__ off,
                                                  int* __restrict__ srt) {
    __shared__ int deg[256];
    __shared__ int loc[256];
    int b = blockIdx.x;
    int beg = goff[b], end = goff[b + 1];
    int tid = threadIdx.x;
    deg[tid] = 0;
    __syncthreads();
    for (int i = beg + tid; i < end; i += 256)
        atomicAdd(&deg[pairs[i].y & 255], 1);
    __syncthreads();
    int v = deg[tid];
    loc[tid] = v;
    __syncthreads();
    for (int st = 1; st < 256; st <<= 1) {
        int t = (tid >= st) ? loc[tid - st] : 0;
        __syncthreads();
        loc[tid] += t;
        __syncthreads();
    }
    int excl = loc[tid] - v + beg;     // global CSR offset for node (b<<8)+tid
    int n = (b << 8) + tid;
    if (n < NN) off[n] = excl;
    __syncthreads();
    deg[tid] = excl;                   // reuse as cursor
    __syncthreads();
    for (int i = beg + tid; i < end; i += 256) {
        uint2 pr = pairs[i];
        int pos = atomicAdd(&deg[pr.y & 255], 1);
        srt[pos] = (int)pr.x;
    }
}

// ---------------------------------------------------------------------------
// Mean aggregation, CSR + chunked. One dispatch per 32-column fp8 chunk p:
// working set = NN*32B = 3.2MB -> resident in each XCD's 4MB L2.
// 4 lanes per node, lane reads uint2 (8 fp8); loads independent, unrolled x4.
// Output stores are NONTEMPORAL (wave dirties full lines; ext-vector type for
// the builtin) so the 6.4MB/pass output stream doesn't evict the L2 slab.
// ---------------------------------------------------------------------------
static __device__ __forceinline__ void acc8(floatx2* ac, uint2 v) {
    ac[0] += __builtin_amdgcn_cvt_pk_f32_fp8((int)v.x, false);
    ac[1] += __builtin_amdgcn_cvt_pk_f32_fp8((int)v.x, true);
    ac[2] += __builtin_amdgcn_cvt_pk_f32_fp8((int)v.y, false);
    ac[3] += __builtin_amdgcn_cvt_pk_f32_fp8((int)v.y, true);
}

__global__ __launch_bounds__(256) void agg_csr(const uint* __restrict__ feat8,
                                               const int* __restrict__ srt,
                                               const int* __restrict__ off,
                                               ushort* __restrict__ aggb, int p) {
    int n = blockIdx.x * 64 + (threadIdx.x >> 2);
    int l = threadIdx.x & 3;
    if (n >= NN) return;
    const uint2* f = (const uint2*)(feat8 + (size_t)p * (NN * 8)) + l;

    int beg = off[n];
    int end = (n < NN - 1) ? off[n + 1] : NE;

    floatx2 ac[4];
    #pragma unroll
    for (int t = 0; t < 4; ++t) ac[t] = (floatx2){0.f, 0.f};

    int i = beg;
    for (; i + 4 <= end; i += 4) {
        int i0 = srt[i], i1 = srt[i + 1], i2 = srt[i + 2], i3 = srt[i + 3];
        uint2 v0 = f[(size_t)i0 * 4];
        uint2 v1 = f[(size_t)i1 * 4];
        uint2 v2 = f[(size_t)i2 * 4];
        uint2 v3 = f[(size_t)i3 * 4];
        acc8(ac, v0);
        acc8(ac, v1);
        acc8(ac, v2);
        acc8(ac, v3);
    }
    for (; i < end; ++i) {
        uint2 v = f[(size_t)srt[i] * 4];
        acc8(ac, v);
    }

    float inv = 1.0f / fmaxf((float)(end - beg), 1.0f);
    uintx4 o;
    o.x = (uint)f2bf(ac[0].x * inv) | ((uint)f2bf(ac[0].y * inv) << 16);
    o.y = (uint)f2bf(ac[1].x * inv) | ((uint)f2bf(ac[1].y * inv) << 16);
    o.z = (uint)f2bf(ac[2].x * inv) | ((uint)f2bf(ac[2].y * inv) << 16);
    o.w = (uint)f2bf(ac[3].x * inv) | ((uint)f2bf(ac[3].y * inv) << 16);
    uintx4* dp = (uintx4*)(aggb + (size_t)n * 128 + p * 32 + l * 8);
    __builtin_nontemporal_store(o, dp);
}

// ---------------------------------------------------------------------------
// Fused GEMM: C[n,j] = act( [agg|self][n,:] @ WT[j,:] + bias[j] ), K=256.
// 512 threads = 8 waves, 128 rows/block. WT staged in LDS (XOR swizzle, 64KB).
// F8OUT: also emit fp8 chunk-major (layer-2 agg input) -> conv_h eliminated.
// ---------------------------------------------------------------------------
template <int RELU, int BF16OUT, int F8OUT>
__global__ __launch_bounds__(512, 4) void gemm_mfma(
        const ushort* __restrict__ aggb, const ushort* __restrict__ selfb,
        const ushort* __restrict__ WT, const float* __restrict__ bias,
        void* __restrict__ outv, uchar* __restrict__ f8out) {
    __shared__ ushort sWT[128 * 256];            // 64KB, swizzled chunks
    const int tid = threadIdx.x;
    const int blk = blockIdx.x;

    #pragma unroll
    for (int it = 0; it < 8; ++it) {
        int flat = it * 512 + tid;               // 0..4095
        int col = flat >> 5;
        int c = flat & 31;
        uint4 v = *(const uint4*)(WT + (size_t)col * 256 + c * 8);
        *(uint4*)&sWT[col * 256 + (c ^ (col & 7)) * 8] = v;
    }

    const int w = tid >> 6;
    const int lane = tid & 63;
    const int m = lane & 15;
    const int q = lane >> 4;

    int node_m = blk * 128 + w * 16 + m;
    int cn = node_m < NN ? node_m : NN - 1;
    const ushort* arow = aggb + (size_t)cn * 128;
    const ushort* xrow = selfb + (size_t)cn * 128;
    short8 a[8];
    #pragma unroll
    for (int kk = 0; kk < 4; ++kk) {
        a[kk]     = *(const short8*)(arow + kk * 32 + q * 8);
        a[4 + kk] = *(const short8*)(xrow + kk * 32 + q * 8);
    }

    __syncthreads();

    floatx4 acc[8];
    #pragma unroll
    for (int t = 0; t < 8; ++t) acc[t] = (floatx4){0.f, 0.f, 0.f, 0.f};

    const int m7 = m & 7;
    #pragma unroll
    for (int kk = 0; kk < 8; ++kk) {
        int cx = (kk * 4 + q) ^ m7;
        #pragma unroll
        for (int t = 0; t < 8; ++t) {
            short8 b = *(const short8*)&sWT[(t * 16 + m) * 256 + cx * 8];
            acc[t] = __builtin_amdgcn_mfma_f32_16x16x32_bf16(a[kk], b, acc[t], 0, 0, 0);
        }
    }

    const int node_base = blk * 128 + w * 16 + q * 4;
    #pragma unroll
    for (int t = 0; t < 8; ++t) {
        int col = t * 16 + m;
        float bj = bias[col];
        #pragma unroll
        for (int r = 0; r < 4; ++r) {
            int node = node_base + r;
            if (node < NN) {
                float v = acc[t][r] + bj;
                if (RELU) v = fmaxf(v, 0.0f);
                if (BF16OUT)
                    ((ushort*)outv)[(size_t)node * 128 + col] = f2bf(v);
                else
                    ((float*)outv)[(size_t)node * 128 + col] = v;
                if (F8OUT) {
                    uint pk = (uint)__builtin_amdgcn_cvt_pk_fp8_f32(v, v, 0, false);
                    f8out[((size_t)(col >> 5) * NN + node) * 32 + (col & 31)] =
                        (uchar)pk;
                }
            }
        }
    }
}

// ---------------------------------------------------------------------------
extern "C" void kernel_launch(void* const* d_in, const int* in_sizes, int n_in,
                              void* d_out, int out_size, void* d_ws, size_t ws_size,
                              hipStream_t stream) {
    const float* x   = (const float*)d_in[0];
    const int*   ei  = (const int*)d_in[1];
    const float* W1l = (const float*)d_in[2];
    const float* b1  = (const float*)d_in[3];
    const float* W1r = (const float*)d_in[4];
    const float* W2l = (const float*)d_in[5];
    const float* b2  = (const float*)d_in[6];
    const float* W2r = (const float*)d_in[7];
    float*       out = (float*)d_out;

    const int* src = ei;
    const int* dst = ei + NE;

    // workspace layout (bytes), total 96.93 MB
    char* ws = (char*)d_ws;
    int*    off  = (int*)(ws);                   // 400000
    int*    srt  = (int*)(ws + 400000);          // 6400000 (ends 6.8MB)
    ushort* WT1  = (ushort*)(ws + 7200000);      // 65536
    ushort* WT2  = (ushort*)(ws + 7265536);      // 65536
    ushort* xb   = (ushort*)(ws + 7331072);      // 25600000
    uint*   xf8c = (uint*)(ws + 32931072);       // 12800000 (chunk-major fp8)
    ushort* aggb = (ushort*)(ws + 45731072);     // 25600000
    ushort* hb   = (ushort*)(ws + 71331072);     // 25600000 (end 96.93MB)
    uchar*  hf8c = (uchar*)xf8c;                 // alias: xf8c dead after agg L1
    // CSR-build temporaries, all dead before aggb is written:
    uint2*  pairs = (uint2*)aggb;                       // 12800000
    int*    gcnt  = (int*)((char*)aggb + 12800000);     // 1564
    int*    goff  = (int*)((char*)aggb + 12801600);     // 1568
    int*    gcur  = (int*)((char*)aggb + 12803200);     // 1564

    // ---- CSR build + input conversion ----
    (void)hipMemsetAsync(gcnt, 0, NBUCK * 4, stream);
    fused_pre<<<CX_BLOCKS + CW_BLOCKS + PB_BLOCKS, 256, 0, stream>>>(
        x, xb, xf8c, W1l, W1r, W2l, W2r, WT1, WT2, dst, gcnt);
    pS_scan<<<1, 512, 0, stream>>>(gcnt, goff, gcur);
    pB_part<<<PB_BLOCKS, 512, 0, stream>>>(src, dst, gcur, pairs);
    pC_scatter<<<NBUCK, 256, 0, stream>>>(pairs, goff, off, srt);

    const int gemm_grid = (NN + 127) / 128;
    const int agg_grid = (NN + 63) / 64;

    // ---- layer 1 ----  (4 serialized chunk passes keep each 3.2MB slab L2-hot)
    for (int p = 0; p < 4; ++p)
        agg_csr<<<agg_grid, 256, 0, stream>>>(xf8c, srt, off, aggb, p);
    gemm_mfma<1, 1, 1><<<gemm_grid, 512, 0, stream>>>(aggb, xb, WT1, b1, hb, hf8c);

    // ---- layer 2 ----
    for (int p = 0; p < 4; ++p)
        agg_csr<<<agg_grid, 256, 0, stream>>>((const uint*)hf8c, srt, off, aggb, p);
    gemm_mfma<0, 0, 0><<<gemm_grid, 512, 0, stream>>>(aggb, hb, WT2, b2, out, nullptr);
}